// Round 1
// baseline (38053.015 us; speedup 1.0000x reference)
//
#include <hip/hip_runtime.h>
#include <hip/hip_bf16.h>
#include <math.h>

// Problem dims
#define PP 400
#define QQ 30
#define BB 32
#define EE 300
#define HH 300
#define FF 300
#define AA 30
#define LL 2

// ---------------------------------------------------------------------------
// Embedding gather: out[row, e] = embed[tok[row], e]
__global__ void gather_embed(const int* __restrict__ tok,
                             const float* __restrict__ embed,
                             float* __restrict__ out, int n_tok) {
    int i = blockIdx.x * blockDim.x + threadIdx.x;
    int n = n_tok * EE;
    if (i >= n) return;
    int row = i / EE, e = i - row * EE;
    out[i] = embed[(size_t)tok[row] * EE + e];
}

// ---------------------------------------------------------------------------
// C[M,N] = A[M,K] @ Bw[N,K]^T + bias[N], optional relu.
// Block 256 threads, 64x64 tile, 4x4 microtile, BK=16.
#define BM 64
#define BN 64
#define BK 16
__global__ void gemm_nt_bias(const float* __restrict__ A,
                             const float* __restrict__ Bw,
                             const float* __restrict__ bias,
                             float* __restrict__ C,
                             int M, int N, int K, int relu) {
    __shared__ float As[BK][BM];
    __shared__ float Bs[BK][BN];
    int tid = threadIdx.x;
    int row0 = blockIdx.y * BM;
    int col0 = blockIdx.x * BN;
    int tx = tid & 15, ty = tid >> 4;
    int lm = tid >> 2;          // 0..63
    int lk = (tid & 3) * 4;     // 0,4,8,12
    float acc[4][4] = {{0.f}};
    for (int k0 = 0; k0 < K; k0 += BK) {
        float4 av = make_float4(0.f, 0.f, 0.f, 0.f);
        int ar = row0 + lm;
        int kk = k0 + lk;
        if (ar < M) {
            if (kk + 3 < K) {
                av = *(const float4*)(A + (size_t)ar * K + kk);
            } else {
                float t0 = (kk + 0 < K) ? A[(size_t)ar * K + kk + 0] : 0.f;
                float t1 = (kk + 1 < K) ? A[(size_t)ar * K + kk + 1] : 0.f;
                float t2 = (kk + 2 < K) ? A[(size_t)ar * K + kk + 2] : 0.f;
                float t3 = (kk + 3 < K) ? A[(size_t)ar * K + kk + 3] : 0.f;
                av = make_float4(t0, t1, t2, t3);
            }
        }
        As[lk + 0][lm] = av.x; As[lk + 1][lm] = av.y;
        As[lk + 2][lm] = av.z; As[lk + 3][lm] = av.w;

        float4 bv = make_float4(0.f, 0.f, 0.f, 0.f);
        int br = col0 + lm;
        if (br < N) {
            if (kk + 3 < K) {
                bv = *(const float4*)(Bw + (size_t)br * K + kk);
            } else {
                float t0 = (kk + 0 < K) ? Bw[(size_t)br * K + kk + 0] : 0.f;
                float t1 = (kk + 1 < K) ? Bw[(size_t)br * K + kk + 1] : 0.f;
                float t2 = (kk + 2 < K) ? Bw[(size_t)br * K + kk + 2] : 0.f;
                float t3 = (kk + 3 < K) ? Bw[(size_t)br * K + kk + 3] : 0.f;
                bv = make_float4(t0, t1, t2, t3);
            }
        }
        Bs[lk + 0][lm] = bv.x; Bs[lk + 1][lm] = bv.y;
        Bs[lk + 2][lm] = bv.z; Bs[lk + 3][lm] = bv.w;
        __syncthreads();
        #pragma unroll
        for (int k = 0; k < BK; k++) {
            float a[4], b[4];
            #pragma unroll
            for (int i = 0; i < 4; i++) a[i] = As[k][ty * 4 + i];
            #pragma unroll
            for (int j = 0; j < 4; j++) b[j] = Bs[k][tx * 4 + j];
            #pragma unroll
            for (int i = 0; i < 4; i++) {
                #pragma unroll
                for (int j = 0; j < 4; j++) acc[i][j] += a[i] * b[j];
            }
        }
        __syncthreads();
    }
    #pragma unroll
    for (int i = 0; i < 4; i++) {
        int r = row0 + ty * 4 + i;
        if (r >= M) continue;
        #pragma unroll
        for (int j = 0; j < 4; j++) {
            int c = col0 + tx * 4 + j;
            if (c >= N) continue;
            float v = acc[i][j] + bias[c];
            if (relu) v = fmaxf(v, 0.f);
            C[(size_t)r * N + c] = v;
        }
    }
}

// ---------------------------------------------------------------------------
// scores[b,p,q] = dot(ff_p[p,b,:], ff_q[q,b,:]) * pm*qm; softmax over q.
// One block of 64 threads per (p,b).
__global__ void scores_softmax(const float* __restrict__ ffp,
                               const float* __restrict__ ffq,
                               const float* __restrict__ p_mask,
                               const float* __restrict__ q_mask,
                               float* __restrict__ weights) {
    int blk = blockIdx.x;          // p*BB + b
    int p = blk / BB, b = blk - p * BB;
    __shared__ float fp[FF];
    __shared__ float sq[QQ];
    for (int f = threadIdx.x; f < FF; f += blockDim.x)
        fp[f] = ffp[(size_t)(p * BB + b) * FF + f];
    __syncthreads();
    int q = threadIdx.x;
    if (q < QQ) {
        const float* fq = ffq + (size_t)(q * BB + b) * FF;
        float s = 0.f;
        for (int f = 0; f < FF; f++) s += fp[f] * fq[f];
        s *= p_mask[p * BB + b] * q_mask[q * BB + b];
        sq[q] = s;
    }
    __syncthreads();
    if (q < QQ) {
        float m = -INFINITY;
        for (int k = 0; k < QQ; k++) m = fmaxf(m, sq[k]);
        float sum = 0.f;
        for (int k = 0; k < QQ; k++) sum += expf(sq[k] - m);
        weights[(size_t)b * PP * QQ + p * QQ + q] = expf(sq[q] - m) / sum;
    }
}

// ---------------------------------------------------------------------------
// x0[p,b,0:E] = p_emb[p,b,:]; x0[p,b,E:2E] = sum_q w[b,p,q]*q_emb[q,b,:]
__global__ void align_concat(const float* __restrict__ weights,
                             const float* __restrict__ q_emb,
                             const float* __restrict__ p_emb,
                             float* __restrict__ x0) {
    int blk = blockIdx.x;          // p*BB + b
    int p = blk / BB, b = blk - p * BB;
    __shared__ float w[QQ];
    if (threadIdx.x < QQ)
        w[threadIdx.x] = weights[(size_t)b * PP * QQ + p * QQ + threadIdx.x];
    __syncthreads();
    for (int e = threadIdx.x; e < EE; e += blockDim.x) {
        float acc = 0.f;
        for (int q = 0; q < QQ; q++)
            acc += w[q] * q_emb[(size_t)(q * BB + b) * EE + e];
        size_t base = (size_t)(p * BB + b) * (2 * EE);
        x0[base + e] = p_emb[(size_t)(p * BB + b) * EE + e];
        x0[base + EE + e] = acc;
    }
}

// ---------------------------------------------------------------------------
// wT[ld][i*900+o] = w_hh[ld][o*300+i]   (ld = l*2+dir, 4 of them)
__global__ void transpose_whh(const float* __restrict__ w_hh,
                              float* __restrict__ wT) {
    int i = blockIdx.x * blockDim.x + threadIdx.x;
    int total = 4 * 900 * 300;
    if (i >= total) return;
    int ld = i / (900 * 300);
    int rem = i - ld * 900 * 300;
    int o = rem / 300, ii = rem - o * 300;
    wT[(size_t)ld * 270000 + ii * 900 + o] = w_hh[i];
}

// ---------------------------------------------------------------------------
// One GRU time step for both directions, all batches. Grid = 64 blocks
// (dir = blk>>5, b = blk&31), 256 threads.
__global__ void gru_step(const float* __restrict__ xp_f,
                         const float* __restrict__ xp_b,
                         const float* __restrict__ wT_f,
                         const float* __restrict__ wT_b,
                         const float* __restrict__ bhh_f,
                         const float* __restrict__ bhh_b,
                         float* __restrict__ h,      // [2,B,H]
                         float* __restrict__ out,    // [P,B,2H]
                         int t) {
    int dir = blockIdx.x >> 5;
    int b = blockIdx.x & 31;
    int te = dir ? (PP - 1 - t) : t;
    const float* xp = (dir ? xp_b : xp_f) + (size_t)(te * BB + b) * 900;
    const float* wT = dir ? wT_b : wT_f;
    const float* bhh = dir ? bhh_b : bhh_f;
    float* hb = h + ((size_t)dir * BB + b) * HH;
    __shared__ float hs[HH];
    __shared__ float gh[900];
    for (int i = threadIdx.x; i < HH; i += blockDim.x) hs[i] = hb[i];
    __syncthreads();
    int o0 = threadIdx.x;   // 0..255
    float a0 = 0.f, a1 = 0.f, a2 = 0.f, a3 = 0.f;
    for (int i = 0; i < HH; i++) {
        float hv = hs[i];
        const float* wrow = wT + (size_t)i * 900;
        a0 += hv * wrow[o0];
        a1 += hv * wrow[o0 + 256];
        a2 += hv * wrow[o0 + 512];
        if (o0 < 132) a3 += hv * wrow[o0 + 768];
    }
    gh[o0] = a0 + bhh[o0];
    gh[o0 + 256] = a1 + bhh[o0 + 256];
    gh[o0 + 512] = a2 + bhh[o0 + 512];
    if (o0 < 132) gh[o0 + 768] = a3 + bhh[o0 + 768];
    __syncthreads();
    for (int j = threadIdx.x; j < HH; j += blockDim.x) {
        float r = 1.f / (1.f + expf(-(xp[j] + gh[j])));
        float z = 1.f / (1.f + expf(-(xp[j + 300] + gh[j + 300])));
        float n = tanhf(xp[j + 600] + r * gh[j + 600]);
        float hn = (1.f - z) * n + z * hs[j];
        hb[j] = hn;
        out[(size_t)(te * BB + b) * (2 * HH) + dir * HH + j] = hn;
    }
}

// ---------------------------------------------------------------------------
// final[b, p*A+j] = (p+j < p_lens[b]) * dot(relu(stt[p,b,:]+end[p+j,b,:]), w_a)
// Block 128 threads (2 waves) per (p,b); each wave does 15 of the 30 j's.
__global__ void span_score(const float* __restrict__ stt,
                           const float* __restrict__ endv,
                           const float* __restrict__ w_a,
                           const int* __restrict__ p_lens,
                           float* __restrict__ final_) {
    int blk = blockIdx.x;          // p*BB + b
    int p = blk / BB, b = blk - p * BB;
    __shared__ float ss[FF];
    __shared__ float wa[FF];
    for (int f = threadIdx.x; f < FF; f += blockDim.x) {
        ss[f] = stt[(size_t)(p * BB + b) * FF + f];
        wa[f] = w_a[f];
    }
    __syncthreads();
    int lane = threadIdx.x & 63, wv = threadIdx.x >> 6;
    int plen = p_lens[b];
    for (int j = wv; j < AA; j += 2) {
        float acc = 0.f;
        int pe = p + j;
        if (pe < PP) {
            const float* ev = endv + (size_t)(pe * BB + b) * FF;
            for (int f = lane; f < FF; f += 64)
                acc += fmaxf(ss[f] + ev[f], 0.f) * wa[f];
        } else {
            for (int f = lane; f < FF; f += 64)
                acc += fmaxf(ss[f], 0.f) * wa[f];
        }
        #pragma unroll
        for (int off = 32; off; off >>= 1) acc += __shfl_down(acc, off);
        if (lane == 0) {
            float v = (pe < plen) ? acc : 0.f;
            final_[(size_t)b * (PP * AA) + p * AA + j] = v;
        }
    }
}

// ---------------------------------------------------------------------------
__global__ void log_softmax_rows(float* __restrict__ out,
                                 const float* __restrict__ final_, int n) {
    int b = blockIdx.x;
    const float* row = final_ + (size_t)b * n;
    __shared__ float red[256];
    float m = -INFINITY;
    for (int i = threadIdx.x; i < n; i += 256) m = fmaxf(m, row[i]);
    red[threadIdx.x] = m;
    __syncthreads();
    for (int s = 128; s; s >>= 1) {
        if (threadIdx.x < s) red[threadIdx.x] = fmaxf(red[threadIdx.x], red[threadIdx.x + s]);
        __syncthreads();
    }
    m = red[0];
    __syncthreads();
    float sum = 0.f;
    for (int i = threadIdx.x; i < n; i += 256) sum += expf(row[i] - m);
    red[threadIdx.x] = sum;
    __syncthreads();
    for (int s = 128; s; s >>= 1) {
        if (threadIdx.x < s) red[threadIdx.x] += red[threadIdx.x + s];
        __syncthreads();
    }
    float lse = m + logf(red[0]);
    for (int i = threadIdx.x; i < n; i += 256) out[(size_t)b * n + i] = row[i] - lse;
}

// ---------------------------------------------------------------------------
extern "C" void kernel_launch(void* const* d_in, const int* in_sizes, int n_in,
                              void* d_out, int out_size, void* d_ws, size_t ws_size,
                              hipStream_t stream) {
    (void)in_sizes; (void)n_in; (void)out_size; (void)ws_size;
    const int*   p_tok  = (const int*)d_in[0];
    const int*   q_tok  = (const int*)d_in[1];
    const float* p_mask = (const float*)d_in[2];
    const float* q_mask = (const float*)d_in[3];
    const int*   p_lens = (const int*)d_in[4];
    // d_in[5] q_lens unused by reference output path
    const float* embed   = (const float*)d_in[6];
    const float* w_align = (const float*)d_in[7];
    const float* b_align = (const float*)d_in[8];
    const float* w_ih    = (const float*)d_in[9];    // [2,2,900,600]
    const float* w_hh    = (const float*)d_in[10];   // [2,2,900,300]
    const float* b_ih    = (const float*)d_in[11];   // [2,2,900]
    const float* b_hh    = (const float*)d_in[12];   // [2,2,900]
    const float* w_stt   = (const float*)d_in[13];
    const float* b_stt   = (const float*)d_in[14];
    const float* w_end   = (const float*)d_in[15];
    const float* b_end   = (const float*)d_in[16];
    const float* w_a     = (const float*)d_in[17];
    float* out = (float*)d_out;
    float* ws = (float*)d_ws;

    // Workspace layout (floats). x1 aliases p_emb+ff_p (dead by GRU time);
    // stt/end alias xp_f (dead after layer-2 recurrence); final aliases scores.
    size_t off = 0;
    float* p_emb = ws + off;  off += (size_t)PP * BB * EE;       // 3,840,000
    float* ff_p  = ws + off;  off += (size_t)PP * BB * FF;       // 3,840,000
    float* q_emb = ws + off;  off += (size_t)QQ * BB * EE;       //   288,000
    float* ff_q  = ws + off;  off += (size_t)QQ * BB * FF;       //   288,000
    float* scores= ws + off;  off += (size_t)BB * PP * QQ;       //   384,000
    float* x0    = ws + off;  off += (size_t)PP * BB * 2 * EE;   // 7,680,000
    float* xp_f  = ws + off;  off += (size_t)PP * BB * 900;      // 11,520,000
    float* xp_b  = ws + off;  off += (size_t)PP * BB * 900;      // 11,520,000
    float* wT    = ws + off;  off += (size_t)4 * 270000;         // 1,080,000
    float* hbuf  = ws + off;  off += (size_t)2 * BB * HH;        //    19,200
    float* x1    = p_emb;       // 7,680,000 spanning p_emb+ff_p
    float* sttb  = xp_f;        // 3,840,000
    float* endb  = xp_f + (size_t)PP * BB * FF;
    float* finalb= scores;      // B*P*A == B*P*Q == 384,000

    const int M = PP * BB;      // 12800
    const int Mq = QQ * BB;     // 960

    // 1. embedding gathers
    gather_embed<<<(M * EE + 255) / 256, 256, 0, stream>>>(p_tok, embed, p_emb, M);
    gather_embed<<<(Mq * EE + 255) / 256, 256, 0, stream>>>(q_tok, embed, q_emb, Mq);

    // 2. aligned-attention projections (relu)
    gemm_nt_bias<<<dim3((FF + BN - 1) / BN, (M + BM - 1) / BM), 256, 0, stream>>>(
        p_emb, w_align, b_align, ff_p, M, FF, EE, 1);
    gemm_nt_bias<<<dim3((FF + BN - 1) / BN, (Mq + BM - 1) / BM), 256, 0, stream>>>(
        q_emb, w_align, b_align, ff_q, Mq, FF, EE, 1);

    // 3. scores + softmax over q
    scores_softmax<<<PP * BB, 64, 0, stream>>>(ff_p, ff_q, p_mask, q_mask, scores);

    // 4. q_align + concat -> x0 = p_star [P,B,600]
    align_concat<<<PP * BB, 256, 0, stream>>>(scores, q_emb, p_emb, x0);

    // 5. pre-transpose w_hh for coalesced recurrent reads
    transpose_whh<<<(4 * 270000 + 255) / 256, 256, 0, stream>>>(w_hh, wT);

    // 6. BiGRU, 2 layers
    for (int l = 0; l < LL; l++) {
        const float* xin = (l == 0) ? x0 : x1;
        float* xout = (l == 0) ? x1 : x0;
        gemm_nt_bias<<<dim3((900 + BN - 1) / BN, (M + BM - 1) / BM), 256, 0, stream>>>(
            xin, w_ih + (size_t)(l * 2 + 0) * 900 * 600, b_ih + (l * 2 + 0) * 900,
            xp_f, M, 900, 600, 0);
        gemm_nt_bias<<<dim3((900 + BN - 1) / BN, (M + BM - 1) / BM), 256, 0, stream>>>(
            xin, w_ih + (size_t)(l * 2 + 1) * 900 * 600, b_ih + (l * 2 + 1) * 900,
            xp_b, M, 900, 600, 0);
        hipMemsetAsync(hbuf, 0, (size_t)2 * BB * HH * sizeof(float), stream);
        for (int t = 0; t < PP; t++) {
            gru_step<<<64, 256, 0, stream>>>(
                xp_f, xp_b,
                wT + (size_t)(l * 2 + 0) * 270000, wT + (size_t)(l * 2 + 1) * 270000,
                b_hh + (l * 2 + 0) * 900, b_hh + (l * 2 + 1) * 900,
                hbuf, xout, t);
        }
    }

    // 7. stt / end projections (relu) from layer-2 output (in x0)
    gemm_nt_bias<<<dim3((FF + BN - 1) / BN, (M + BM - 1) / BM), 256, 0, stream>>>(
        x0, w_stt, b_stt, sttb, M, FF, 2 * HH, 1);
    gemm_nt_bias<<<dim3((FF + BN - 1) / BN, (M + BM - 1) / BM), 256, 0, stream>>>(
        x0, w_end, b_end, endb, M, FF, 2 * HH, 1);

    // 8. span scores
    span_score<<<PP * BB, 128, 0, stream>>>(sttb, endb, w_a, p_lens, finalb);

    // 9. log-softmax rows -> out
    log_softmax_rows<<<BB, 256, 0, stream>>>(out, finalb, PP * AA);
}